// Round 2
// baseline (274.721 us; speedup 1.0000x reference)
//
#include <hip/hip_runtime.h>

#define B_ 8
#define N_ 1568
#define C_ 384
#define H_ 6
#define D_ 64
#define BH_ 48
#define SZ_ (B_*H_*N_*D_)
#define EPS_ 1e-6f
#define CSC_ 0.18033688011112042f  /* D^-0.5 * log2(e) */

typedef short s16x8 __attribute__((ext_vector_type(8)));
typedef short s16x4 __attribute__((ext_vector_type(4)));
typedef float f32x4 __attribute__((ext_vector_type(4)));

static __device__ __forceinline__ ushort f2bf(float f){
  union { float f; unsigned u; } v; v.f = f;
  unsigned r = v.u + 0x7fffu + ((v.u >> 16) & 1u);
  return (ushort)(r >> 16);
}
static __device__ __forceinline__ unsigned cvtpk(float lo, float hi){
  unsigned r;
  asm("v_cvt_pk_bf16_f32 %0, %1, %2" : "=v"(r) : "v"(lo), "v"(hi));
  return r;
}
#define MFMA16(a,b,c) __builtin_amdgcn_mfma_f32_16x16x32_bf16((a),(b),(c),0,0,0)

#if __has_builtin(__builtin_amdgcn_exp2f)
#define EXP2F(x) __builtin_amdgcn_exp2f(x)
#else
#define EXP2F(x) exp2f(x)
#endif

// ---------------- convert f32 -> bf16 for X, w_qkv, w_proj in one launch ----------------
#define XV8_ 602112   /* 12544*384/8 */
#define WQ8_ 55296    /* 1152*384/8 */
#define WP8_ 18432    /* 384*384/8  */
__global__ __launch_bounds__(256) void cvt_all(const float* __restrict__ X, const float* __restrict__ Wq,
                                               const float* __restrict__ Wp, ushort* __restrict__ Xb,
                                               ushort* __restrict__ Wqb, ushort* __restrict__ Wpb){
  int i = blockIdx.x*256 + threadIdx.x;
  const float* src; ushort* dst; int off;
  if (i < XV8_)            { src = X;  dst = Xb;  off = i; }
  else if (i < XV8_+WQ8_)  { src = Wq; dst = Wqb; off = i - XV8_; }
  else                     { src = Wp; dst = Wpb; off = i - XV8_ - WQ8_; }
  float4 a = ((const float4*)src)[off*2];
  float4 b = ((const float4*)src)[off*2+1];
  s16x8 r;
  r[0]=(short)f2bf(a.x); r[1]=(short)f2bf(a.y); r[2]=(short)f2bf(a.z); r[3]=(short)f2bf(a.w);
  r[4]=(short)f2bf(b.x); r[5]=(short)f2bf(b.y); r[6]=(short)f2bf(b.z); r[7]=(short)f2bf(b.w);
  *(s16x8*)&dst[off*8] = r;
}

// ---------------- QKV GEMM (bf16 direct-from-global, no LDS): qkv = Xb @ Wqb^T ----------------
__global__ __launch_bounds__(256) void qkv_gemm(const ushort* __restrict__ Xb, const ushort* __restrict__ Wb,
                                                ushort* __restrict__ Qg, ushort* __restrict__ Kg,
                                                ushort* __restrict__ Vg){
  const int tid = threadIdx.x, lane = tid&63, w = tid>>6;
  const int g = lane>>4, lr = lane&15;
  const int wr = w>>1, wc = w&1;
  const int m0 = blockIdx.x*128, j0 = blockIdx.y*64;
  f32x4 acc[4][2];
  #pragma unroll
  for (int i=0;i<4;i++){ acc[i][0]=(f32x4){0,0,0,0}; acc[i][1]=(f32x4){0,0,0,0}; }
  for (int ks=0; ks<384; ks+=32){
    s16x8 af[4], bf[2];
    #pragma unroll
    for (int fm=0; fm<4; fm++)
      af[fm] = *(const s16x8*)&Xb[(size_t)(m0+wr*64+fm*16+lr)*384 + ks + g*8];
    #pragma unroll
    for (int fn=0; fn<2; fn++)
      bf[fn] = *(const s16x8*)&Wb[(size_t)(j0+wc*32+fn*16+lr)*384 + ks + g*8];
    #pragma unroll
    for (int fm=0; fm<4; fm++)
      #pragma unroll
      for (int fn=0; fn<2; fn++)
        acc[fm][fn] = MFMA16(af[fm], bf[fn], acc[fm][fn]);
  }
  const int t = j0/384, h = (j0%384)/64;
  #pragma unroll
  for (int fm=0; fm<4; fm++){
    #pragma unroll
    for (int jj=0; jj<4; jj++){
      int m = m0 + wr*64 + fm*16 + g*4 + jj;
      int bi = m / N_; int n = m - bi*N_;
      #pragma unroll
      for (int fn=0; fn<2; fn++){
        int d = wc*32 + fn*16 + lr;
        float v = acc[fm][fn][jj];
        int idx = ((bi*H_ + h)*N_ + n)*64 + d;
        if (t==0)      Qg[idx] = f2bf(v * CSC_);
        else if (t==1) Kg[idx] = f2bf(v);
        else           Vg[idx] = f2bf(v);
      }
    }
  }
}

// ---------------- fused flash attention, swapped-QK^T, in-register softmax ----------------
__global__ __launch_bounds__(256) void attn_fwd(const ushort* __restrict__ Qg, const ushort* __restrict__ Kg,
                                                const ushort* __restrict__ Vg, const float* __restrict__ pol_g,
                                                ushort* __restrict__ AO){
  __shared__ __align__(16) ushort Kl[64*64];   // row-major [key][d], byte ^ ((key&7)<<4)
  __shared__ __align__(16) ushort Vt[64*64];   // transposed [d][key], byte ^ ((d&7)<<4)
  __shared__ __align__(16) float  pm_s[64];

  const int tid = threadIdx.x, lane = tid&63, w = tid>>6;
  const int g = lane>>4, lr = lane&15;
  const int bh = blockIdx.x; const int b = bh / H_, h = bh - b*H_;
  const int qrow0 = blockIdx.y*64 + w*16;
  const int q = qrow0 + lr;
  const int qc = q < N_ ? q : N_-1;
  const ushort* Qrow = Qg + ((size_t)bh*N_ + qc)*64;
  const s16x8 qf0 = *(const s16x8*)(Qrow + g*8);
  const s16x8 qf1 = *(const s16x8*)(Qrow + 32 + g*8);
  const float* polp = pol_g + b*N_;

  const int sr = tid>>2;          // staging row (key)
  const int sc = (tid&3)*2;       // two 16B chunks per thread
  const int swzK = (sr&7)<<4;
  const int sl0 = ((lane>>4)&1)<<5 | lr;   // bpermute source lanes
  const int sl1 = sl0 + 16;

  f32x4 o[4];
  #pragma unroll
  for (int i=0;i<4;i++) o[i] = (f32x4){0,0,0,0};
  float M = -INFINITY, L = 0.f;

  for (int t0=0; t0<N_; t0+=64){
    // ---- stage K (swizzled row-major) + V (swizzled transposed) ----
    int krow = t0 + sr; krow = krow < N_ ? krow : N_-1;
    const size_t kb = ((size_t)bh*N_ + krow)*64;
    s16x8 k0 = *(const s16x8*)(Kg + kb + sc*8);
    s16x8 k1 = *(const s16x8*)(Kg + kb + sc*8 + 8);
    *(s16x8*)((char*)Kl + sr*128 + ((sc*16) ^ swzK))     = k0;
    *(s16x8*)((char*)Kl + sr*128 + (((sc+1)*16) ^ swzK)) = k1;
    s16x8 v0 = *(const s16x8*)(Vg + kb + sc*8);
    s16x8 v1 = *(const s16x8*)(Vg + kb + sc*8 + 8);
    #pragma unroll
    for (int i=0;i<8;i++){
      int d0 = sc*8 + i, d1 = sc*8 + 8 + i;
      *(ushort*)((char*)Vt + d0*128 + ((2*sr) ^ ((d0&7)<<4))) = (ushort)v0[i];
      *(ushort*)((char*)Vt + d1*128 + ((2*sr) ^ ((d1&7)<<4))) = (ushort)v1[i];
    }
    if (tid < 64) pm_s[tid] = (t0+tid < N_) ? polp[t0+tid] : 0.f;
    __syncthreads();

    // ---- S^T = K Q^T : st[kg][jj] = logit(q=qrow0+lr, key=t0+kg*16+4g+jj), log2-scaled ----
    f32x4 st[4];
    const int swzR = (lr&7)<<4;
    #pragma unroll
    for (int kg=0; kg<4; kg++){
      const char* krowp = (const char*)Kl + (kg*16+lr)*128;
      s16x8 kf0 = *(const s16x8*)(krowp + ((g*16) ^ swzR));
      s16x8 kf1 = *(const s16x8*)(krowp + ((64 + g*16) ^ swzR));
      f32x4 z = (f32x4){0,0,0,0};
      z = MFMA16(kf0, qf0, z);
      st[kg] = MFMA16(kf1, qf1, z);
    }

    // ---- online softmax (per-lane row q), defer-max THR=8 ----
    float pmax;
    {
      float m0 = fmaxf(fmaxf(st[0][0],st[0][1]), fmaxf(st[0][2],st[0][3]));
      float m1 = fmaxf(fmaxf(st[1][0],st[1][1]), fmaxf(st[1][2],st[1][3]));
      float m2 = fmaxf(fmaxf(st[2][0],st[2][1]), fmaxf(st[2][2],st[2][3]));
      float m3 = fmaxf(fmaxf(st[3][0],st[3][1]), fmaxf(st[3][2],st[3][3]));
      pmax = fmaxf(fmaxf(m0,m1), fmaxf(m2,m3));
      pmax = fmaxf(pmax, __shfl_xor(pmax, 16));
      pmax = fmaxf(pmax, __shfl_xor(pmax, 32));
    }
    if (__any(pmax > M + 8.f)){
      float Mn = fmaxf(M, pmax);
      float corr = EXP2F(M - Mn);
      L *= corr;
      #pragma unroll
      for (int fd=0; fd<4; fd++){ o[fd][0]*=corr; o[fd][1]*=corr; o[fd][2]*=corr; o[fd][3]*=corr; }
      M = Mn;
    }
    const bool dg = (qrow0 & ~63) == t0;   // diagonal lives in this tile
    #pragma unroll
    for (int kg=0; kg<4; kg++){
      float4 pmv = *(const float4*)&pm_s[kg*16 + 4*g];
      if (dg){
        #pragma unroll
        for (int jj=0; jj<4; jj++){
          float e = EXP2F(st[kg][jj] - M);
          float em = e * ((&pmv.x)[jj]);
          int key = t0 + kg*16 + 4*g + jj;
          st[kg][jj] = (key == q) ? e : em;
        }
      } else {
        #pragma unroll
        for (int jj=0; jj<4; jj++){
          float e = EXP2F(st[kg][jj] - M);
          st[kg][jj] = e * ((&pmv.x)[jj]);
        }
      }
    }
    {
      float se = (st[0][0]+st[0][1]) + (st[0][2]+st[0][3]);
      se += (st[1][0]+st[1][1]) + (st[1][2]+st[1][3]);
      se += (st[2][0]+st[2][1]) + (st[2][2]+st[2][3]);
      se += (st[3][0]+st[3][1]) + (st[3][2]+st[3][3]);
      se += __shfl_xor(se, 16);
      se += __shfl_xor(se, 32);
      L += se;
    }

    // ---- pack P to bf16 pairs, redistribute to B-fragments via bpermute ----
    unsigned pk[4][2];
    #pragma unroll
    for (int kg=0; kg<4; kg++){
      pk[kg][0] = cvtpk(st[kg][0], st[kg][1]);
      pk[kg][1] = cvtpk(st[kg][2], st[kg][3]);
    }
    union { unsigned u[4]; s16x8 v; } bfr[2];
    #pragma unroll
    for (int kh=0; kh<2; kh++){
      #pragma unroll
      for (int wd=0; wd<4; wd++){
        int srcl = (wd < 2) ? sl0 : sl1;
        unsigned a0 = (unsigned)__shfl((int)pk[2*kh][wd&1],   srcl);
        unsigned a1 = (unsigned)__shfl((int)pk[2*kh+1][wd&1], srcl);
        bfr[kh].u[wd] = (g < 2) ? a0 : a1;
      }
    }

    // ---- O^T += V^T P^T ----
    #pragma unroll
    for (int fd=0; fd<4; fd++){
      const char* vrow = (const char*)Vt + (fd*16+lr)*128;
      s16x8 va0 = *(const s16x8*)(vrow + ((g*16) ^ swzR));
      s16x8 va1 = *(const s16x8*)(vrow + ((64 + g*16) ^ swzR));
      o[fd] = MFMA16(va0, bfr[0].v, o[fd]);
      o[fd] = MFMA16(va1, bfr[1].v, o[fd]);
    }
    __syncthreads();
  }

  // ---- epilogue: normalize, write AO[b,q, h*64 + d] (d = fd*16+4g+jj) ----
  if (q < N_){
    float inv = 1.f / (L + EPS_);
    ushort* aop = AO + ((size_t)b*N_ + q)*C_ + h*64 + 4*g;
    #pragma unroll
    for (int fd=0; fd<4; fd++){
      s16x4 r;
      r[0]=(short)f2bf(o[fd][0]*inv); r[1]=(short)f2bf(o[fd][1]*inv);
      r[2]=(short)f2bf(o[fd][2]*inv); r[3]=(short)f2bf(o[fd][3]*inv);
      *(s16x4*)(aop + fd*16) = r;
    }
  }
}

// ---------------- proj GEMM (bf16 direct-from-global): out = AO @ Wpb^T + b, f32 out ----------------
__global__ __launch_bounds__(256) void proj_gemm(const ushort* __restrict__ A, const ushort* __restrict__ Wb,
                                                 const float* __restrict__ bias, float* __restrict__ out){
  const int tid = threadIdx.x, lane = tid&63, w = tid>>6;
  const int g = lane>>4, lr = lane&15;
  const int wr = w>>1, wc = w&1;
  const int m0 = blockIdx.x*128, j0 = blockIdx.y*64;
  f32x4 acc[4][2];
  #pragma unroll
  for (int i=0;i<4;i++){ acc[i][0]=(f32x4){0,0,0,0}; acc[i][1]=(f32x4){0,0,0,0}; }
  for (int ks=0; ks<384; ks+=32){
    s16x8 af[4], bf[2];
    #pragma unroll
    for (int fm=0; fm<4; fm++)
      af[fm] = *(const s16x8*)&A[(size_t)(m0+wr*64+fm*16+lr)*384 + ks + g*8];
    #pragma unroll
    for (int fn=0; fn<2; fn++)
      bf[fn] = *(const s16x8*)&Wb[(size_t)(j0+wc*32+fn*16+lr)*384 + ks + g*8];
    #pragma unroll
    for (int fm=0; fm<4; fm++)
      #pragma unroll
      for (int fn=0; fn<2; fn++)
        acc[fm][fn] = MFMA16(af[fm], bf[fn], acc[fm][fn]);
  }
  float bs0 = bias[j0 + wc*32 + lr];
  float bs1 = bias[j0 + wc*32 + 16 + lr];
  #pragma unroll
  for (int fm=0; fm<4; fm++){
    #pragma unroll
    for (int jj=0; jj<4; jj++){
      int m = m0 + wr*64 + fm*16 + g*4 + jj;
      out[(size_t)m*384 + j0 + wc*32 + lr]      = acc[fm][0][jj] + bs0;
      out[(size_t)m*384 + j0 + wc*32 + 16 + lr] = acc[fm][1][jj] + bs1;
    }
  }
}

extern "C" void kernel_launch(void* const* d_in, const int* in_sizes, int n_in,
                              void* d_out, int out_size, void* d_ws, size_t ws_size,
                              hipStream_t stream) {
  const float* x     = (const float*)d_in[0];
  const float* vis   = (const float*)d_in[1];
  const float* wqkv  = (const float*)d_in[2];
  const float* wproj = (const float*)d_in[3];
  const float* bproj = (const float*)d_in[4];
  float* out = (float*)d_out;

  ushort* Qg  = (ushort*)d_ws;
  ushort* Kg  = Qg + SZ_;
  ushort* Vg  = Kg + SZ_;
  ushort* AO  = Vg + SZ_;          // aliased: Xb during qkv phase, AO afterwards
  ushort* Xb  = AO;
  ushort* Wqb = AO + SZ_;
  ushort* Wpb = Wqb + 3*C_*C_;

  cvt_all<<<2640, 256, 0, stream>>>(x, wqkv, wproj, Xb, Wqb, Wpb);
  qkv_gemm<<<dim3(98,18), 256, 0, stream>>>(Xb, Wqb, Qg, Kg, Vg);
  attn_fwd<<<dim3(48,25), 256, 0, stream>>>(Qg, Kg, Vg, vis, AO);
  proj_gemm<<<dim3(98,6), 256, 0, stream>>>(AO, Wpb, bproj, out);
}